// Round 20
// baseline (142.452 us; speedup 1.0000x reference)
//
#include <hip/hip_runtime.h>

using u16 = unsigned short;
typedef __attribute__((ext_vector_type(8))) short short8;
typedef __attribute__((ext_vector_type(4))) float f32x4;

__device__ __forceinline__ float b2f(u16 u){ union{unsigned u; float f;} c; c.u = ((unsigned)u) << 16; return c.f; }
__device__ __forceinline__ u16 f2b(float f){
  union{float f; unsigned u;} c; c.f = f;
  unsigned r = 0x7fffu + ((c.u >> 16) & 1u);
  return (u16)((c.u + r) >> 16);
}

#define GLOAD_LDS16(g, l) __builtin_amdgcn_global_load_lds( \
  (const __attribute__((address_space(1))) unsigned int*)(g), \
  (__attribute__((address_space(3))) unsigned int*)(l), 16, 0, 0)

// ---------- fused: blocks < n4/256 do f32->bf16 cvt; next 768 permute Wqkv; last 256 Wcomb ----------
__global__ __launch_bounds__(256) void k_cvt_prep(const float4* __restrict__ in, ushort4* __restrict__ out, int n4,
    const float* __restrict__ w, const float* __restrict__ w_lin, const float* __restrict__ w_out,
    const float* __restrict__ b_out, const float* __restrict__ b_lin,
    u16* __restrict__ wq, float* __restrict__ wcf, float* __restrict__ bc){
  const int nblk = n4 >> 8;
  int b = blockIdx.x, i = threadIdx.x;
  if (b < nblk){
    int idx = b * 256 + i;
    float4 v = in[idx];
    ushort4 o; o.x = f2b(v.x); o.y = f2b(v.y); o.z = f2b(v.z); o.w = f2b(v.w);
    out[idx] = o;
    return;
  }
  int r = b - nblk;
  if (r < 768){
    int src;
    if (r < 256) src = r;
    else { int g = r - 256, p4 = g >> 7, o = g & 127;
           src = (o < 64) ? 256 + p4*64 + o : 512 + p4*64 + (o - 64); }
    wq[r*256 + i] = f2b(w[src*256 + i]);
  } else {
    int l = r - 768;
    float s = 0.f;
    for (int j = 0; j < 256; ++j) s += w_lin[l*256 + j] * w_out[j*256 + i];
    wcf[l*256 + i] = s;
    __shared__ float red[256];
    red[i] = w_lin[l*256 + i] * b_out[i];
    __syncthreads();
    for (int off = 128; off > 0; off >>= 1){ if (i < off) red[i] += red[i + off]; __syncthreads(); }
    if (i == 0) bc[l] = red[0] + b_lin[l];
  }
}

// ---------- fused QKV GEMM ----------
// bn 0,1: q -> LDS transpose -> per-head no-max softmax*scale -> qs [M][256]
// bn 2..5: ek|v for 2 heads -> transposed LDS tiles -> MFMA ctx+Z; XCD-local slotted atomics
__global__ __launch_bounds__(256, 3) void k_gemm_qkv(const u16* __restrict__ A, const u16* __restrict__ B,
    u16* __restrict__ qs, float* __restrict__ ctxu, float* __restrict__ zu, int M){
  constexpr int K = 256, NT = 8;
  __shared__ __align__(16) u16 pool[24576];   // staging 48KB; epilogue overlays
  u16* As = pool;            // 3 x 4096
  u16* Bs = pool + 12288;    // 3 x 4096
  const int t = threadIdx.x;
  const int wave = t >> 6, lane = t & 63;
  const int bi = blockIdx.x;
  const int xk = bi & 7, bj = bi >> 3;
  const int bm = (xk + 8*(bj/6)) * 128;
  const int bn = bj % 6;
  const int srow = wave*32 + (lane>>2);
  const int skel = (((lane&3) ^ ((lane>>3)&3)) << 3);
  const u16* ag = A + (size_t)(bm + srow)*K + skel;
  const u16* bg = B + (size_t)(bn*128 + srow)*K + skel;
  const size_t rstep = (size_t)16*K;
  const int wr = (wave>>1)*64, wc4 = (wave&1)*64;
  const int fr = lane & 15;
  const int fkc = lane >> 4;
  const int koff = ((fkc ^ ((fr>>1)&3)) << 3);
  f32x4 acc[4][4] = {};
  #pragma unroll
  for (int pre = 0; pre < 2; ++pre){
    u16* asl = As + pre*4096 + wave*1024; u16* bsl = Bs + pre*4096 + wave*1024;
    const int k0 = pre*32;
    GLOAD_LDS16(ag + k0,         asl);
    GLOAD_LDS16(ag + rstep + k0, asl + 512);
    GLOAD_LDS16(bg + k0,         bsl);
    GLOAD_LDS16(bg + rstep + k0, bsl + 512);
  }
  #pragma unroll
  for (int it = 0; it < NT; ++it){
    const int cur = it % 3;
    if (it == NT-1) { asm volatile("s_waitcnt vmcnt(0)" ::: "memory"); }
    else            { asm volatile("s_waitcnt vmcnt(4)" ::: "memory"); }
    __builtin_amdgcn_s_barrier();
    __builtin_amdgcn_sched_barrier(0);
    short8 av[4], bv[4];
    #pragma unroll
    for (int m = 0; m < 4; ++m)
      av[m] = *(const short8*)&As[cur*4096 + (wr + m*16 + fr)*32 + koff];
    #pragma unroll
    for (int n = 0; n < 4; ++n)
      bv[n] = *(const short8*)&Bs[cur*4096 + (wc4 + n*16 + fr)*32 + koff];
    if (it + 2 < NT){
      const int nb = (it+2) % 3;
      u16* asl = As + nb*4096 + wave*1024; u16* bsl = Bs + nb*4096 + wave*1024;
      const int k0 = (it+2)*32;
      GLOAD_LDS16(ag + k0,         asl);
      GLOAD_LDS16(ag + rstep + k0, asl + 512);
      GLOAD_LDS16(bg + k0,         bsl);
      GLOAD_LDS16(bg + rstep + k0, bsl + 512);
    }
    __builtin_amdgcn_s_setprio(1);
    #pragma unroll
    for (int m = 0; m < 4; ++m)
      #pragma unroll
      for (int n = 0; n < 4; ++n)
        acc[m][n] = __builtin_amdgcn_mfma_f32_16x16x32_bf16(av[m], bv[n], acc[m][n], 0, 0, 0);
    __builtin_amdgcn_s_setprio(0);
  }
  __syncthreads();               // all waves done reading staging LDS
  const int lr0 = wr + (lane>>4)*4;
  if (bn < 2){
    u16* cmat = pool;
    #pragma unroll
    for (int m = 0; m < 4; ++m)
      #pragma unroll
      for (int n = 0; n < 4; ++n)
        #pragma unroll
        for (int r = 0; r < 4; ++r)
          cmat[(lr0 + m*16 + r)*136 + wc4 + n*16 + fr] = f2b(acc[m][n][r]);
    __syncthreads();
    const int row = t >> 1, co = (t & 1) * 64;
    #pragma unroll
    for (int hh = 0; hh < 2; ++hh){
      float f[32];
      #pragma unroll
      for (int c4 = 0; c4 < 4; ++c4){
        short8 w = *(const short8*)&cmat[row*136 + co + hh*32 + c4*8];
        #pragma unroll
        for (int k2 = 0; k2 < 8; ++k2) f[c4*8+k2] = b2f((u16)w[k2]);
      }
      float sum = 0.f;
      #pragma unroll
      for (int i2 = 0; i2 < 32; ++i2){ float e = __expf(f[i2]); f[i2] = e; sum += e; }
      float sc = 0.17677669529663689f / sum;
      #pragma unroll
      for (int c4 = 0; c4 < 4; ++c4){
        short8 o;
        #pragma unroll
        for (int k2 = 0; k2 < 8; ++k2) o[k2] = (short)f2b(f[c4*8+k2] * sc);
        *(short8*)&qs[(size_t)(bm+row)*256 + bn*128 + co + hh*32 + c4*8] = o;
      }
    }
  } else {
    u16* ekT = pool;               // [64][136]  row=ch(hl*32+dd), col=token
    u16* vT  = pool + 64*136;      // [64][136]
    const bool isK = (wc4 == 0);
    #pragma unroll
    for (int m = 0; m < 4; ++m)
      #pragma unroll
      for (int n = 0; n < 4; ++n)
        #pragma unroll
        for (int r = 0; r < 4; ++r){
          int row = lr0 + m*16 + r;      // token
          int csub = n*16 + fr;          // channel within half
          if (isK) ekT[csub*136 + row] = f2b(__expf(acc[m][n][r]));
          else     vT [csub*136 + row] = f2b(acc[m][n][r]);
        }
    __syncthreads();
    const int hl = wave >> 1, ti = wave & 1;
    const int head = (bn - 2)*2 + hl;
    short8 ones;
    #pragma unroll
    for (int j = 0; j < 8; ++j) ones[j] = (short)0x3F80;
    f32x4 acc2[2] = {}; f32x4 zacc = {};
    #pragma unroll
    for (int kc = 0; kc < 4; ++kc){
      const int ko2 = kc*32 + fkc*8;
      short8 av2 = *(const short8*)&ekT[(hl*32 + ti*16 + fr)*136 + ko2];
      short8 bv0 = *(const short8*)&vT [(hl*32 +         fr)*136 + ko2];
      short8 bv1 = *(const short8*)&vT [(hl*32 + 16 +    fr)*136 + ko2];
      acc2[0] = __builtin_amdgcn_mfma_f32_16x16x32_bf16(av2, bv0, acc2[0], 0, 0, 0);
      acc2[1] = __builtin_amdgcn_mfma_f32_16x16x32_bf16(av2, bv1, acc2[1], 0, 0, 0);
      zacc    = __builtin_amdgcn_mfma_f32_16x16x32_bf16(av2, ones, zacc, 0, 0, 0);
    }
    const int frame = bm / 9216;
    const int slot = xk;   // XCD-local slot: all writers of a slot share an XCD L2
    float* cb = ctxu + (((size_t)frame*8 + slot)*8 + head)*1024;
    const int drow = ti*16 + (lane>>4)*4;
    #pragma unroll
    for (int tj = 0; tj < 2; ++tj)
      #pragma unroll
      for (int rr = 0; rr < 4; ++rr)
        atomicAdd(&cb[(drow + rr)*32 + tj*16 + fr], acc2[tj][rr]);
    if (fr == 0){
      float* zb = zu + (((size_t)frame*8 + slot)*8 + head)*32;
      #pragma unroll
      for (int rr = 0; rr < 4; ++rr)
        atomicAdd(&zb[drow + rr], zacc[rr]);
    }
  }
}

// ---------- output GEMM: out = qs @ Weff_f^T + bc + resid, LDS-transpose epilogue ----------
__global__ __launch_bounds__(256, 3) void k_gemm_out(const u16* __restrict__ A, const u16* __restrict__ B,
    float* __restrict__ Cf, const float* __restrict__ bias, const u16* __restrict__ residb,
    int M, int NB, int frame_rows){
  constexpr int K = 256, N = 256, NT = 8;
  __shared__ __align__(16) u16 pool[24576];
  u16* As = pool;
  u16* Bs = pool + 12288;
  const int t = threadIdx.x;
  const int wave = t >> 6, lane = t & 63;
  const int bi = blockIdx.x;
  const int xk = bi & 7, bj = bi >> 3;
  const int bm = (xk + 8*(bj/NB)) * 128, bn = (bj%NB) * 128;
  if (frame_rows > 0) B += (size_t)(bm / frame_rows) * N * K;
  const int srow = wave*32 + (lane>>2);
  const int skel = (((lane&3) ^ ((lane>>3)&3)) << 3);
  const u16* ag = A + (size_t)(bm + srow)*K + skel;
  const u16* bg = B + (size_t)(bn + srow)*K + skel;
  const size_t rstep = (size_t)16*K;
  const int wr = (wave>>1)*64, wc4 = (wave&1)*64;
  const int fr = lane & 15;
  const int fkc = lane >> 4;
  const int koff = ((fkc ^ ((fr>>1)&3)) << 3);
  f32x4 acc[4][4] = {};
  #pragma unroll
  for (int pre = 0; pre < 2; ++pre){
    u16* asl = As + pre*4096 + wave*1024; u16* bsl = Bs + pre*4096 + wave*1024;
    const int k0 = pre*32;
    GLOAD_LDS16(ag + k0,         asl);
    GLOAD_LDS16(ag + rstep + k0, asl + 512);
    GLOAD_LDS16(bg + k0,         bsl);
    GLOAD_LDS16(bg + rstep + k0, bsl + 512);
  }
  #pragma unroll
  for (int it = 0; it < NT; ++it){
    const int cur = it % 3;
    if (it == NT-1) { asm volatile("s_waitcnt vmcnt(0)" ::: "memory"); }
    else            { asm volatile("s_waitcnt vmcnt(4)" ::: "memory"); }
    __builtin_amdgcn_s_barrier();
    __builtin_amdgcn_sched_barrier(0);
    short8 av[4], bv[4];
    #pragma unroll
    for (int m = 0; m < 4; ++m)
      av[m] = *(const short8*)&As[cur*4096 + (wr + m*16 + fr)*32 + koff];
    #pragma unroll
    for (int n = 0; n < 4; ++n)
      bv[n] = *(const short8*)&Bs[cur*4096 + (wc4 + n*16 + fr)*32 + koff];
    if (it + 2 < NT){
      const int nb = (it+2) % 3;
      u16* asl = As + nb*4096 + wave*1024; u16* bsl = Bs + nb*4096 + wave*1024;
      const int k0 = (it+2)*32;
      GLOAD_LDS16(ag + k0,         asl);
      GLOAD_LDS16(ag + rstep + k0, asl + 512);
      GLOAD_LDS16(bg + k0,         bsl);
      GLOAD_LDS16(bg + rstep + k0, bsl + 512);
    }
    __builtin_amdgcn_s_setprio(1);
    #pragma unroll
    for (int m = 0; m < 4; ++m)
      #pragma unroll
      for (int n = 0; n < 4; ++n)
        acc[m][n] = __builtin_amdgcn_mfma_f32_16x16x32_bf16(av[m], bv[n], acc[m][n], 0, 0, 0);
    __builtin_amdgcn_s_setprio(0);
  }
  __syncthreads();
  float* cmatf = (float*)pool;
  const int lr0 = (lane>>4)*4;
  float biasr[32];
  {
    const int c0 = bn + (t&3)*32;
    #pragma unroll
    for (int c4 = 0; c4 < 8; ++c4)
      *(float4*)&biasr[c4*4] = *(const float4*)&bias[c0 + c4*4];
  }
  #pragma unroll
  for (int half = 0; half < 2; ++half){
    if ((wr >> 6) == half){
      #pragma unroll
      for (int m = 0; m < 4; ++m)
        #pragma unroll
        for (int n = 0; n < 4; ++n)
          #pragma unroll
          for (int r = 0; r < 4; ++r)
            cmatf[(lr0 + m*16 + r)*132 + wc4 + n*16 + fr] = acc[m][n][r];
    }
    __syncthreads();
    {
      const int row = t >> 2, seg = (t & 3) * 32;
      const int gr = bm + half*64 + row;
      const size_t gbase = (size_t)gr*256 + bn + seg;
      float v[32];
      #pragma unroll
      for (int c4 = 0; c4 < 8; ++c4)
        *(float4*)&v[c4*4] = *(const float4*)&cmatf[row*132 + seg + c4*4];
      #pragma unroll
      for (int c4 = 0; c4 < 4; ++c4){
        short8 rr = *(const short8*)&residb[gbase + c4*8];
        #pragma unroll
        for (int k2 = 0; k2 < 8; ++k2)
          v[c4*8+k2] += biasr[c4*8+k2] + b2f((u16)rr[k2]);
      }
      #pragma unroll
      for (int c4 = 0; c4 < 8; ++c4)
        *(float4*)&Cf[gbase + c4*4] = *(float4*)&v[c4*4];
    }
    __syncthreads();
  }
}

// ---------- Weff: grid (8h, 8f); per-block slot-sum ONCE into LDS, then 256 l rows ----------
__global__ __launch_bounds__(256) void k_weff(const float* __restrict__ ctxu, const float* __restrict__ zu,
    const float* __restrict__ wcf, u16* __restrict__ weff){
  const int h = blockIdx.x, frel = blockIdx.y, t = threadIdx.x;
  __shared__ float cs[1024];
  __shared__ float izv[32];
  for (int i = t; i < 1024; i += 256){
    float s = 0.f;
    #pragma unroll
    for (int sl = 0; sl < 8; ++sl) s += ctxu[(((size_t)frel*8 + sl)*8 + h)*1024 + i];
    cs[i] = s;
  }
  if (t < 32){
    float z = 0.f;
    #pragma unroll
    for (int sl = 0; sl < 8; ++sl) z += zu[(((size_t)frel*8 + sl)*8 + h)*32 + t];
    izv[t] = 1.0f / z;
  }
  __syncthreads();
  const float* wr = wcf + (size_t)t*256 + h*32;
  float wv[32];
  #pragma unroll
  for (int e = 0; e < 32; ++e) wv[e] = wr[e];
  u16* dst = &weff[((size_t)frel*256 + t)*256 + h*32];
  #pragma unroll
  for (int d4 = 0; d4 < 4; ++d4){
    short8 o;
    #pragma unroll
    for (int j = 0; j < 8; ++j){
      const int dd = d4*8 + j;
      const float* cr = &cs[dd*32];
      float s = 0.f;
      #pragma unroll
      for (int e = 0; e < 32; ++e) s += cr[e] * wv[e];
      o[j] = (short)f2b(s * izv[dd]);
    }
    *(short8*)&dst[d4*8] = o;
  }
}

extern "C" void kernel_launch(void* const* d_in, const int* in_sizes, int n_in,
                              void* d_out, int out_size, void* d_ws, size_t ws_size,
                              hipStream_t stream){
  const float* x     = (const float*)d_in[0];
  const float* w_qkv = (const float*)d_in[1];
  const float* w_out = (const float*)d_in[2];
  const float* b_out = (const float*)d_in[3];
  const float* w_lin = (const float*)d_in[4];
  const float* b_lin = (const float*)d_in[5];
  float* out = (float*)d_out;

  char* p = (char*)d_ws;
  u16*   wqb   = (u16*)p;   p += (size_t)768*256*2;
  float* wcf   = (float*)p; p += (size_t)256*256*4;
  float* bc    = (float*)p; p += 256*4;
  float* ctxu  = (float*)p; p += (size_t)8*8*8192*4;   // [f][slot][8][1024]
  float* zu    = (float*)p; p += (size_t)8*8*256*4;    // [f][slot][8][32]
  u16*   weffb = (u16*)p;   p += (size_t)8*256*256*2;
  size_t fixed = (size_t)(p - (char*)d_ws);
  size_t per_frame = (size_t)2 * 9216*256*2;   // xb + qs
  int chunk = (ws_size >= fixed + 8*per_frame) ? 8 : 1;
  u16* xb  = (u16*)p;
  u16* qsb = xb  + (size_t)chunk*9216*256;

  // zero atomic accumulators (ctxu + zu contiguous)
  hipMemsetAsync(ctxu, 0, (size_t)8*8*8192*4 + (size_t)8*8*256*4, stream);

  for (int f0 = 0; f0 < 8; f0 += chunk){
    const float* xc = x  + (size_t)f0*9216*256;
    float*       oc = out + (size_t)f0*9216*256;
    const int M = chunk * 9216;
    const int n4 = M * 256 / 4;
    const int extra = (f0 == 0) ? 1024 : 0;   // weight-prep blocks only on first pass
    hipLaunchKernelGGL(k_cvt_prep, dim3(n4/256 + extra), dim3(256), 0, stream,
                       (const float4*)xc, (ushort4*)xb, n4,
                       w_qkv, w_lin, w_out, b_out, b_lin, wqb, wcf, bc);
    hipLaunchKernelGGL(k_gemm_qkv, dim3((M/128)*6), dim3(256), 0, stream,
                       xb, wqb, qsb, ctxu + (size_t)f0*8*8192, zu + (size_t)f0*8*256, M);
    hipLaunchKernelGGL(k_weff, dim3(8, chunk), dim3(256), 0, stream,
                       ctxu + (size_t)f0*8*8192, zu + (size_t)f0*8*256, wcf, weffb + (size_t)f0*256*256);
    hipLaunchKernelGGL(k_gemm_out, dim3((M/128)*2), dim3(256), 0, stream,
                       qsb, weffb + (size_t)f0*256*256, oc, bc, xb,
                       M, 2, (chunk == 8) ? 9216 : 0);
  }
}

// Round 21
// 140.129 us; speedup vs baseline: 1.0166x; 1.0166x over previous
//
#include <hip/hip_runtime.h>

using u16 = unsigned short;
typedef __attribute__((ext_vector_type(8))) short short8;
typedef __attribute__((ext_vector_type(4))) float f32x4;

__device__ __forceinline__ float b2f(u16 u){ union{unsigned u; float f;} c; c.u = ((unsigned)u) << 16; return c.f; }
__device__ __forceinline__ u16 f2b(float f){
  union{float f; unsigned u;} c; c.f = f;
  unsigned r = 0x7fffu + ((c.u >> 16) & 1u);
  return (u16)((c.u + r) >> 16);
}

#define GLOAD_LDS16(g, l) __builtin_amdgcn_global_load_lds( \
  (const __attribute__((address_space(1))) unsigned int*)(g), \
  (__attribute__((address_space(3))) unsigned int*)(l), 16, 0, 0)

// ---------- f32 -> bf16 convert, 4/thread ----------
__global__ void k_cvt(const float4* __restrict__ in, ushort4* __restrict__ out, int n4){
  int i = blockIdx.x * 256 + threadIdx.x;
  if (i < n4){
    float4 v = in[i];
    ushort4 o; o.x = f2b(v.x); o.y = f2b(v.y); o.z = f2b(v.z); o.w = f2b(v.w);
    out[i] = o;
  }
}

// ---------- merged weight prep: blocks 0..767 cvt+permute Wqkv; 768..1023 Wcomb/bcomb ----------
__global__ __launch_bounds__(256) void k_prep(const float* __restrict__ w,
    const float* __restrict__ w_lin, const float* __restrict__ w_out,
    const float* __restrict__ b_out, const float* __restrict__ b_lin,
    u16* __restrict__ wq, float* __restrict__ wcf, float* __restrict__ bc){
  int r = blockIdx.x, i = threadIdx.x;
  if (r < 768){
    int src;
    if (r < 256) src = r;
    else { int g = r - 256, p4 = g >> 7, o = g & 127;
           src = (o < 64) ? 256 + p4*64 + o : 512 + p4*64 + (o - 64); }
    wq[r*256 + i] = f2b(w[src*256 + i]);
  } else {
    int l = r - 768;
    float s = 0.f;
    for (int j = 0; j < 256; ++j) s += w_lin[l*256 + j] * w_out[j*256 + i];
    wcf[l*256 + i] = s;
    __shared__ float red[256];
    red[i] = w_lin[l*256 + i] * b_out[i];
    __syncthreads();
    for (int off = 128; off > 0; off >>= 1){ if (i < off) red[i] += red[i + off]; __syncthreads(); }
    if (i == 0) bc[l] = red[0] + b_lin[l];
  }
}

// ---------- fused QKV GEMM ----------
// bn 0,1: q -> LDS transpose -> per-head no-max softmax*scale -> qs [M][256]
// bn 2..5: ek|v for 2 heads -> transposed LDS tiles -> MFMA ctx+Z; 16-slot atomics
__global__ __launch_bounds__(256, 3) void k_gemm_qkv(const u16* __restrict__ A, const u16* __restrict__ B,
    u16* __restrict__ qs, float* __restrict__ ctxu, float* __restrict__ zu, int M){
  constexpr int K = 256, NT = 8;
  __shared__ __align__(16) u16 pool[24576];   // staging 48KB; epilogue overlays
  u16* As = pool;            // 3 x 4096
  u16* Bs = pool + 12288;    // 3 x 4096
  const int t = threadIdx.x;
  const int wave = t >> 6, lane = t & 63;
  const int bi = blockIdx.x;
  const int xk = bi & 7, bj = bi >> 3;
  const int bm = (xk + 8*(bj/6)) * 128;
  const int bn = bj % 6;
  const int srow = wave*32 + (lane>>2);
  const int skel = (((lane&3) ^ ((lane>>3)&3)) << 3);
  const u16* ag = A + (size_t)(bm + srow)*K + skel;
  const u16* bg = B + (size_t)(bn*128 + srow)*K + skel;
  const size_t rstep = (size_t)16*K;
  const int wr = (wave>>1)*64, wc4 = (wave&1)*64;
  const int fr = lane & 15;
  const int fkc = lane >> 4;
  const int koff = ((fkc ^ ((fr>>1)&3)) << 3);
  f32x4 acc[4][4] = {};
  #pragma unroll
  for (int pre = 0; pre < 2; ++pre){
    u16* asl = As + pre*4096 + wave*1024; u16* bsl = Bs + pre*4096 + wave*1024;
    const int k0 = pre*32;
    GLOAD_LDS16(ag + k0,         asl);
    GLOAD_LDS16(ag + rstep + k0, asl + 512);
    GLOAD_LDS16(bg + k0,         bsl);
    GLOAD_LDS16(bg + rstep + k0, bsl + 512);
  }
  #pragma unroll
  for (int it = 0; it < NT; ++it){
    const int cur = it % 3;
    if (it == NT-1) { asm volatile("s_waitcnt vmcnt(0)" ::: "memory"); }
    else            { asm volatile("s_waitcnt vmcnt(4)" ::: "memory"); }
    __builtin_amdgcn_s_barrier();
    __builtin_amdgcn_sched_barrier(0);
    short8 av[4], bv[4];
    #pragma unroll
    for (int m = 0; m < 4; ++m)
      av[m] = *(const short8*)&As[cur*4096 + (wr + m*16 + fr)*32 + koff];
    #pragma unroll
    for (int n = 0; n < 4; ++n)
      bv[n] = *(const short8*)&Bs[cur*4096 + (wc4 + n*16 + fr)*32 + koff];
    if (it + 2 < NT){
      const int nb = (it+2) % 3;
      u16* asl = As + nb*4096 + wave*1024; u16* bsl = Bs + nb*4096 + wave*1024;
      const int k0 = (it+2)*32;
      GLOAD_LDS16(ag + k0,         asl);
      GLOAD_LDS16(ag + rstep + k0, asl + 512);
      GLOAD_LDS16(bg + k0,         bsl);
      GLOAD_LDS16(bg + rstep + k0, bsl + 512);
    }
    __builtin_amdgcn_s_setprio(1);
    #pragma unroll
    for (int m = 0; m < 4; ++m)
      #pragma unroll
      for (int n = 0; n < 4; ++n)
        acc[m][n] = __builtin_amdgcn_mfma_f32_16x16x32_bf16(av[m], bv[n], acc[m][n], 0, 0, 0);
    __builtin_amdgcn_s_setprio(0);
  }
  __syncthreads();               // all waves done reading staging LDS
  const int lr0 = wr + (lane>>4)*4;
  if (bn < 2){
    u16* cmat = pool;
    #pragma unroll
    for (int m = 0; m < 4; ++m)
      #pragma unroll
      for (int n = 0; n < 4; ++n)
        #pragma unroll
        for (int r = 0; r < 4; ++r)
          cmat[(lr0 + m*16 + r)*136 + wc4 + n*16 + fr] = f2b(acc[m][n][r]);
    __syncthreads();
    const int row = t >> 1, co = (t & 1) * 64;
    #pragma unroll
    for (int hh = 0; hh < 2; ++hh){
      float f[32];
      #pragma unroll
      for (int c4 = 0; c4 < 4; ++c4){
        short8 w = *(const short8*)&cmat[row*136 + co + hh*32 + c4*8];
        #pragma unroll
        for (int k2 = 0; k2 < 8; ++k2) f[c4*8+k2] = b2f((u16)w[k2]);
      }
      float sum = 0.f;
      #pragma unroll
      for (int i2 = 0; i2 < 32; ++i2){ float e = __expf(f[i2]); f[i2] = e; sum += e; }
      float sc = 0.17677669529663689f / sum;
      #pragma unroll
      for (int c4 = 0; c4 < 4; ++c4){
        short8 o;
        #pragma unroll
        for (int k2 = 0; k2 < 8; ++k2) o[k2] = (short)f2b(f[c4*8+k2] * sc);
        *(short8*)&qs[(size_t)(bm+row)*256 + bn*128 + co + hh*32 + c4*8] = o;
      }
    }
  } else {
    u16* ekT = pool;               // [64][136]  row=ch(hl*32+dd), col=token
    u16* vT  = pool + 64*136;      // [64][136]
    const bool isK = (wc4 == 0);
    #pragma unroll
    for (int m = 0; m < 4; ++m)
      #pragma unroll
      for (int n = 0; n < 4; ++n)
        #pragma unroll
        for (int r = 0; r < 4; ++r){
          int row = lr0 + m*16 + r;      // token
          int csub = n*16 + fr;          // channel within half
          if (isK) ekT[csub*136 + row] = f2b(__expf(acc[m][n][r]));
          else     vT [csub*136 + row] = f2b(acc[m][n][r]);
        }
    __syncthreads();
    const int hl = wave >> 1, ti = wave & 1;
    const int head = (bn - 2)*2 + hl;
    short8 ones;
    #pragma unroll
    for (int j = 0; j < 8; ++j) ones[j] = (short)0x3F80;
    f32x4 acc2[2] = {}; f32x4 zacc = {};
    #pragma unroll
    for (int kc = 0; kc < 4; ++kc){
      const int ko2 = kc*32 + fkc*8;
      short8 av2 = *(const short8*)&ekT[(hl*32 + ti*16 + fr)*136 + ko2];
      short8 bv0 = *(const short8*)&vT [(hl*32 +         fr)*136 + ko2];
      short8 bv1 = *(const short8*)&vT [(hl*32 + 16 +    fr)*136 + ko2];
      acc2[0] = __builtin_amdgcn_mfma_f32_16x16x32_bf16(av2, bv0, acc2[0], 0, 0, 0);
      acc2[1] = __builtin_amdgcn_mfma_f32_16x16x32_bf16(av2, bv1, acc2[1], 0, 0, 0);
      zacc    = __builtin_amdgcn_mfma_f32_16x16x32_bf16(av2, ones, zacc, 0, 0, 0);
    }
    const int frame = bm / 9216;
    const int slot = ((bm % 9216) >> 7) & 15;   // 16 slots: ~4.5 writers per address
    float* cb = ctxu + (((size_t)frame*16 + slot)*8 + head)*1024;
    const int drow = ti*16 + (lane>>4)*4;
    #pragma unroll
    for (int tj = 0; tj < 2; ++tj)
      #pragma unroll
      for (int rr = 0; rr < 4; ++rr)
        atomicAdd(&cb[(drow + rr)*32 + tj*16 + fr], acc2[tj][rr]);
    if (fr == 0){
      float* zb = zu + (((size_t)frame*16 + slot)*8 + head)*32;
      #pragma unroll
      for (int rr = 0; rr < 4; ++rr)
        atomicAdd(&zb[drow + rr], zacc[rr]);
    }
  }
}

// ---------- output GEMM: out = qs @ Weff_f^T + bc + resid, LDS-transpose epilogue ----------
__global__ __launch_bounds__(256, 3) void k_gemm_out(const u16* __restrict__ A, const u16* __restrict__ B,
    float* __restrict__ Cf, const float* __restrict__ bias, const u16* __restrict__ residb,
    int M, int NB, int frame_rows){
  constexpr int K = 256, N = 256, NT = 8;
  __shared__ __align__(16) u16 pool[24576];
  u16* As = pool;
  u16* Bs = pool + 12288;
  const int t = threadIdx.x;
  const int wave = t >> 6, lane = t & 63;
  const int bi = blockIdx.x;
  const int xk = bi & 7, bj = bi >> 3;
  const int bm = (xk + 8*(bj/NB)) * 128, bn = (bj%NB) * 128;
  if (frame_rows > 0) B += (size_t)(bm / frame_rows) * N * K;
  const int srow = wave*32 + (lane>>2);
  const int skel = (((lane&3) ^ ((lane>>3)&3)) << 3);
  const u16* ag = A + (size_t)(bm + srow)*K + skel;
  const u16* bg = B + (size_t)(bn + srow)*K + skel;
  const size_t rstep = (size_t)16*K;
  const int wr = (wave>>1)*64, wc4 = (wave&1)*64;
  const int fr = lane & 15;
  const int fkc = lane >> 4;
  const int koff = ((fkc ^ ((fr>>1)&3)) << 3);
  f32x4 acc[4][4] = {};
  #pragma unroll
  for (int pre = 0; pre < 2; ++pre){
    u16* asl = As + pre*4096 + wave*1024; u16* bsl = Bs + pre*4096 + wave*1024;
    const int k0 = pre*32;
    GLOAD_LDS16(ag + k0,         asl);
    GLOAD_LDS16(ag + rstep + k0, asl + 512);
    GLOAD_LDS16(bg + k0,         bsl);
    GLOAD_LDS16(bg + rstep + k0, bsl + 512);
  }
  #pragma unroll
  for (int it = 0; it < NT; ++it){
    const int cur = it % 3;
    if (it == NT-1) { asm volatile("s_waitcnt vmcnt(0)" ::: "memory"); }
    else            { asm volatile("s_waitcnt vmcnt(4)" ::: "memory"); }
    __builtin_amdgcn_s_barrier();
    __builtin_amdgcn_sched_barrier(0);
    short8 av[4], bv[4];
    #pragma unroll
    for (int m = 0; m < 4; ++m)
      av[m] = *(const short8*)&As[cur*4096 + (wr + m*16 + fr)*32 + koff];
    #pragma unroll
    for (int n = 0; n < 4; ++n)
      bv[n] = *(const short8*)&Bs[cur*4096 + (wc4 + n*16 + fr)*32 + koff];
    if (it + 2 < NT){
      const int nb = (it+2) % 3;
      u16* asl = As + nb*4096 + wave*1024; u16* bsl = Bs + nb*4096 + wave*1024;
      const int k0 = (it+2)*32;
      GLOAD_LDS16(ag + k0,         asl);
      GLOAD_LDS16(ag + rstep + k0, asl + 512);
      GLOAD_LDS16(bg + k0,         bsl);
      GLOAD_LDS16(bg + rstep + k0, bsl + 512);
    }
    __builtin_amdgcn_s_setprio(1);
    #pragma unroll
    for (int m = 0; m < 4; ++m)
      #pragma unroll
      for (int n = 0; n < 4; ++n)
        acc[m][n] = __builtin_amdgcn_mfma_f32_16x16x32_bf16(av[m], bv[n], acc[m][n], 0, 0, 0);
    __builtin_amdgcn_s_setprio(0);
  }
  __syncthreads();
  float* cmatf = (float*)pool;
  const int lr0 = (lane>>4)*4;
  float biasr[32];
  {
    const int c0 = bn + (t&3)*32;
    #pragma unroll
    for (int c4 = 0; c4 < 8; ++c4)
      *(float4*)&biasr[c4*4] = *(const float4*)&bias[c0 + c4*4];
  }
  #pragma unroll
  for (int half = 0; half < 2; ++half){
    if ((wr >> 6) == half){
      #pragma unroll
      for (int m = 0; m < 4; ++m)
        #pragma unroll
        for (int n = 0; n < 4; ++n)
          #pragma unroll
          for (int r = 0; r < 4; ++r)
            cmatf[(lr0 + m*16 + r)*132 + wc4 + n*16 + fr] = acc[m][n][r];
    }
    __syncthreads();
    {
      const int row = t >> 2, seg = (t & 3) * 32;
      const int gr = bm + half*64 + row;
      const size_t gbase = (size_t)gr*256 + bn + seg;
      float v[32];
      #pragma unroll
      for (int c4 = 0; c4 < 8; ++c4)
        *(float4*)&v[c4*4] = *(const float4*)&cmatf[row*132 + seg + c4*4];
      #pragma unroll
      for (int c4 = 0; c4 < 4; ++c4){
        short8 rr = *(const short8*)&residb[gbase + c4*8];
        #pragma unroll
        for (int k2 = 0; k2 < 8; ++k2)
          v[c4*8+k2] += biasr[c4*8+k2] + b2f((u16)rr[k2]);
      }
      #pragma unroll
      for (int c4 = 0; c4 < 8; ++c4)
        *(float4*)&Cf[gbase + c4*4] = *(float4*)&v[c4*4];
    }
    __syncthreads();
  }
}

// ---------- Weff: grid (8h, 8f); per-block 16-slot sum ONCE into LDS, then 256 l rows ----------
__global__ __launch_bounds__(256) void k_weff(const float* __restrict__ ctxu, const float* __restrict__ zu,
    const float* __restrict__ wcf, u16* __restrict__ weff){
  const int h = blockIdx.x, frel = blockIdx.y, t = threadIdx.x;
  __shared__ float cs[1024];
  __shared__ float izv[32];
  for (int i = t; i < 1024; i += 256){
    float s = 0.f;
    #pragma unroll
    for (int sl = 0; sl < 16; ++sl) s += ctxu[(((size_t)frel*16 + sl)*8 + h)*1024 + i];
    cs[i] = s;
  }
  if (t < 32){
    float z = 0.f;
    #pragma unroll
    for (int sl = 0; sl < 16; ++sl) z += zu[(((size_t)frel*16 + sl)*8 + h)*32 + t];
    izv[t] = 1.0f / z;
  }
  __syncthreads();
  const float* wr = wcf + (size_t)t*256 + h*32;
  float wv[32];
  #pragma unroll
  for (int e = 0; e < 32; ++e) wv[e] = wr[e];
  u16* dst = &weff[((size_t)frel*256 + t)*256 + h*32];
  #pragma unroll
  for (int d4 = 0; d4 < 4; ++d4){
    short8 o;
    #pragma unroll
    for (int j = 0; j < 8; ++j){
      const int dd = d4*8 + j;
      const float* cr = &cs[dd*32];
      float s = 0.f;
      #pragma unroll
      for (int e = 0; e < 32; ++e) s += cr[e] * wv[e];
      o[j] = (short)f2b(s * izv[dd]);
    }
    *(short8*)&dst[d4*8] = o;
  }
}

extern "C" void kernel_launch(void* const* d_in, const int* in_sizes, int n_in,
                              void* d_out, int out_size, void* d_ws, size_t ws_size,
                              hipStream_t stream){
  const float* x     = (const float*)d_in[0];
  const float* w_qkv = (const float*)d_in[1];
  const float* w_out = (const float*)d_in[2];
  const float* b_out = (const float*)d_in[3];
  const float* w_lin = (const float*)d_in[4];
  const float* b_lin = (const float*)d_in[5];
  float* out = (float*)d_out;

  char* p = (char*)d_ws;
  u16*   wqb   = (u16*)p;   p += (size_t)768*256*2;
  float* wcf   = (float*)p; p += (size_t)256*256*4;
  float* bc    = (float*)p; p += 256*4;
  float* ctxu  = (float*)p; p += (size_t)8*16*8192*4;   // [f][slot16][8][1024]
  float* zu    = (float*)p; p += (size_t)8*16*256*4;    // [f][slot16][8][32]
  u16*   weffb = (u16*)p;   p += (size_t)8*256*256*2;
  size_t fixed = (size_t)(p - (char*)d_ws);
  size_t per_frame = (size_t)2 * 9216*256*2;   // xb + qs
  int chunk = (ws_size >= fixed + 8*per_frame) ? 8 : 1;
  u16* xb  = (u16*)p;
  u16* qsb = xb  + (size_t)chunk*9216*256;

  // zero atomic accumulators (ctxu + zu contiguous)
  hipMemsetAsync(ctxu, 0, (size_t)8*16*8192*4 + (size_t)8*16*256*4, stream);

  // weight prep (once)
  hipLaunchKernelGGL(k_prep, dim3(1024), dim3(256), 0, stream,
                     w_qkv, w_lin, w_out, b_out, b_lin, wqb, wcf, bc);

  for (int f0 = 0; f0 < 8; f0 += chunk){
    const float* xc = x  + (size_t)f0*9216*256;
    float*       oc = out + (size_t)f0*9216*256;
    const int M = chunk * 9216;
    const int n4 = M * 256 / 4;
    hipLaunchKernelGGL(k_cvt, dim3((n4 + 255)/256), dim3(256), 0, stream, (const float4*)xc, (ushort4*)xb, n4);
    hipLaunchKernelGGL(k_gemm_qkv, dim3((M/128)*6), dim3(256), 0, stream,
                       xb, wqb, qsb, ctxu + (size_t)f0*16*8192, zu + (size_t)f0*16*256, M);
    hipLaunchKernelGGL(k_weff, dim3(8, chunk), dim3(256), 0, stream,
                       ctxu + (size_t)f0*16*8192, zu + (size_t)f0*16*256, wcf, weffb + (size_t)f0*256*256);
    hipLaunchKernelGGL(k_gemm_out, dim3((M/128)*2), dim3(256), 0, stream,
                       qsb, weffb + (size_t)f0*256*256, oc, bc, xb,
                       M, 2, (chunk == 8) ? 9216 : 0);
  }
}

// Round 22
// 138.561 us; speedup vs baseline: 1.0281x; 1.0113x over previous
//
#include <hip/hip_runtime.h>

using u16 = unsigned short;
typedef __attribute__((ext_vector_type(8))) short short8;
typedef __attribute__((ext_vector_type(4))) float f32x4;

__device__ __forceinline__ float b2f(u16 u){ union{unsigned u; float f;} c; c.u = ((unsigned)u) << 16; return c.f; }
__device__ __forceinline__ u16 f2b(float f){
  union{float f; unsigned u;} c; c.f = f;
  unsigned r = 0x7fffu + ((c.u >> 16) & 1u);
  return (u16)((c.u + r) >> 16);
}

#define GLOAD_LDS16(g, l) __builtin_amdgcn_global_load_lds( \
  (const __attribute__((address_space(1))) unsigned int*)(g), \
  (__attribute__((address_space(3))) unsigned int*)(l), 16, 0, 0)

// ---------- f32 -> bf16 convert, 4/thread ----------
__global__ void k_cvt(const float4* __restrict__ in, ushort4* __restrict__ out, int n4){
  int i = blockIdx.x * 256 + threadIdx.x;
  if (i < n4){
    float4 v = in[i];
    ushort4 o; o.x = f2b(v.x); o.y = f2b(v.y); o.z = f2b(v.z); o.w = f2b(v.w);
    out[i] = o;
  }
}

// ---------- merged weight prep: blocks 0..767 cvt+permute Wqkv; 768..1023 Wcomb/bcomb ----------
__global__ __launch_bounds__(256) void k_prep(const float* __restrict__ w,
    const float* __restrict__ w_lin, const float* __restrict__ w_out,
    const float* __restrict__ b_out, const float* __restrict__ b_lin,
    u16* __restrict__ wq, float* __restrict__ wcf, float* __restrict__ bc){
  int r = blockIdx.x, i = threadIdx.x;
  if (r < 768){
    int src;
    if (r < 256) src = r;
    else { int g = r - 256, p4 = g >> 7, o = g & 127;
           src = (o < 64) ? 256 + p4*64 + o : 512 + p4*64 + (o - 64); }
    wq[r*256 + i] = f2b(w[src*256 + i]);
  } else {
    int l = r - 768;
    float s = 0.f;
    for (int j = 0; j < 256; ++j) s += w_lin[l*256 + j] * w_out[j*256 + i];
    wcf[l*256 + i] = s;
    __shared__ float red[256];
    red[i] = w_lin[l*256 + i] * b_out[i];
    __syncthreads();
    for (int off = 128; off > 0; off >>= 1){ if (i < off) red[i] += red[i + off]; __syncthreads(); }
    if (i == 0) bc[l] = red[0] + b_lin[l];
  }
}

// ---------- fused QKV GEMM ----------
// bn 0,1: q -> LDS transpose -> per-head no-max softmax*scale -> qs [M][256]
// bn 2..5: ek|v for 2 heads -> transposed LDS tiles (packed b64 writes) -> MFMA ctx+Z; atomics
__global__ __launch_bounds__(256, 3) void k_gemm_qkv(const u16* __restrict__ A, const u16* __restrict__ B,
    u16* __restrict__ qs, float* __restrict__ ctxu, float* __restrict__ zu, int M){
  constexpr int K = 256, NT = 8;
  __shared__ __align__(16) u16 pool[24576];   // staging 48KB; epilogue overlays
  u16* As = pool;            // 3 x 4096
  u16* Bs = pool + 12288;    // 3 x 4096
  const int t = threadIdx.x;
  const int wave = t >> 6, lane = t & 63;
  const int bi = blockIdx.x;
  const int xk = bi & 7, bj = bi >> 3;
  const int bm = (xk + 8*(bj/6)) * 128;
  const int bn = bj % 6;
  const int srow = wave*32 + (lane>>2);
  const int skel = (((lane&3) ^ ((lane>>3)&3)) << 3);
  const u16* ag = A + (size_t)(bm + srow)*K + skel;
  const u16* bg = B + (size_t)(bn*128 + srow)*K + skel;
  const size_t rstep = (size_t)16*K;
  const int wr = (wave>>1)*64, wc4 = (wave&1)*64;
  const int fr = lane & 15;
  const int fkc = lane >> 4;
  const int koff = ((fkc ^ ((fr>>1)&3)) << 3);
  f32x4 acc[4][4] = {};
  #pragma unroll
  for (int pre = 0; pre < 2; ++pre){
    u16* asl = As + pre*4096 + wave*1024; u16* bsl = Bs + pre*4096 + wave*1024;
    const int k0 = pre*32;
    GLOAD_LDS16(ag + k0,         asl);
    GLOAD_LDS16(ag + rstep + k0, asl + 512);
    GLOAD_LDS16(bg + k0,         bsl);
    GLOAD_LDS16(bg + rstep + k0, bsl + 512);
  }
  #pragma unroll
  for (int it = 0; it < NT; ++it){
    const int cur = it % 3;
    if (it == NT-1) { asm volatile("s_waitcnt vmcnt(0)" ::: "memory"); }
    else            { asm volatile("s_waitcnt vmcnt(4)" ::: "memory"); }
    __builtin_amdgcn_s_barrier();
    __builtin_amdgcn_sched_barrier(0);
    short8 av[4], bv[4];
    #pragma unroll
    for (int m = 0; m < 4; ++m)
      av[m] = *(const short8*)&As[cur*4096 + (wr + m*16 + fr)*32 + koff];
    #pragma unroll
    for (int n = 0; n < 4; ++n)
      bv[n] = *(const short8*)&Bs[cur*4096 + (wc4 + n*16 + fr)*32 + koff];
    if (it + 2 < NT){
      const int nb = (it+2) % 3;
      u16* asl = As + nb*4096 + wave*1024; u16* bsl = Bs + nb*4096 + wave*1024;
      const int k0 = (it+2)*32;
      GLOAD_LDS16(ag + k0,         asl);
      GLOAD_LDS16(ag + rstep + k0, asl + 512);
      GLOAD_LDS16(bg + k0,         bsl);
      GLOAD_LDS16(bg + rstep + k0, bsl + 512);
    }
    __builtin_amdgcn_s_setprio(1);
    #pragma unroll
    for (int m = 0; m < 4; ++m)
      #pragma unroll
      for (int n = 0; n < 4; ++n)
        acc[m][n] = __builtin_amdgcn_mfma_f32_16x16x32_bf16(av[m], bv[n], acc[m][n], 0, 0, 0);
    __builtin_amdgcn_s_setprio(0);
  }
  __syncthreads();               // all waves done reading staging LDS
  const int lr0 = wr + (lane>>4)*4;
  if (bn < 2){
    u16* cmat = pool;
    #pragma unroll
    for (int m = 0; m < 4; ++m)
      #pragma unroll
      for (int n = 0; n < 4; ++n)
        #pragma unroll
        for (int r = 0; r < 4; ++r)
          cmat[(lr0 + m*16 + r)*136 + wc4 + n*16 + fr] = f2b(acc[m][n][r]);
    __syncthreads();
    const int row = t >> 1, co = (t & 1) * 64;
    #pragma unroll
    for (int hh = 0; hh < 2; ++hh){
      float f[32];
      #pragma unroll
      for (int c4 = 0; c4 < 4; ++c4){
        short8 w = *(const short8*)&cmat[row*136 + co + hh*32 + c4*8];
        #pragma unroll
        for (int k2 = 0; k2 < 8; ++k2) f[c4*8+k2] = b2f((u16)w[k2]);
      }
      float sum = 0.f;
      #pragma unroll
      for (int i2 = 0; i2 < 32; ++i2){ float e = __expf(f[i2]); f[i2] = e; sum += e; }
      float sc = 0.17677669529663689f / sum;
      #pragma unroll
      for (int c4 = 0; c4 < 4; ++c4){
        short8 o;
        #pragma unroll
        for (int k2 = 0; k2 < 8; ++k2) o[k2] = (short)f2b(f[c4*8+k2] * sc);
        *(short8*)&qs[(size_t)(bm+row)*256 + bn*128 + co + hh*32 + c4*8] = o;
      }
    }
  } else {
    // KV block: cols 0-63 = k (2 heads, exp), 64-127 = v. Packed b64 transposed writes.
    u16* ekT = pool;               // [64][136]  row=ch(hl*32+dd), col=token
    u16* vT  = pool + 64*136;      // [64][136]
    const bool isK = (wc4 == 0);
    u16* dst = isK ? ekT : vT;
    #pragma unroll
    for (int m = 0; m < 4; ++m)
      #pragma unroll
      for (int n = 0; n < 4; ++n){
        const int row = lr0 + m*16;          // token base (r contiguous)
        const int csub = n*16 + fr;          // channel within half
        uint2 pk;
        if (isK){
          pk.x = (unsigned)f2b(__expf(acc[m][n][0])) | ((unsigned)f2b(__expf(acc[m][n][1])) << 16);
          pk.y = (unsigned)f2b(__expf(acc[m][n][2])) | ((unsigned)f2b(__expf(acc[m][n][3])) << 16);
        } else {
          pk.x = (unsigned)f2b(acc[m][n][0]) | ((unsigned)f2b(acc[m][n][1]) << 16);
          pk.y = (unsigned)f2b(acc[m][n][2]) | ((unsigned)f2b(acc[m][n][3]) << 16);
        }
        *(uint2*)&dst[csub*136 + row] = pk;
      }
    __syncthreads();
    const int hl = wave >> 1, ti = wave & 1;
    const int head = (bn - 2)*2 + hl;
    short8 ones;
    #pragma unroll
    for (int j = 0; j < 8; ++j) ones[j] = (short)0x3F80;
    f32x4 acc2[2] = {}; f32x4 zacc = {};
    #pragma unroll
    for (int kc = 0; kc < 4; ++kc){
      const int ko2 = kc*32 + fkc*8;
      short8 av2 = *(const short8*)&ekT[(hl*32 + ti*16 + fr)*136 + ko2];
      short8 bv0 = *(const short8*)&vT [(hl*32 +         fr)*136 + ko2];
      short8 bv1 = *(const short8*)&vT [(hl*32 + 16 +    fr)*136 + ko2];
      acc2[0] = __builtin_amdgcn_mfma_f32_16x16x32_bf16(av2, bv0, acc2[0], 0, 0, 0);
      acc2[1] = __builtin_amdgcn_mfma_f32_16x16x32_bf16(av2, bv1, acc2[1], 0, 0, 0);
      zacc    = __builtin_amdgcn_mfma_f32_16x16x32_bf16(av2, ones, zacc, 0, 0, 0);
    }
    const int frame = bm / 9216;
    const int slot = ((bm % 9216) >> 7) & 7;
    float* cb = ctxu + (((size_t)frame*8 + slot)*8 + head)*1024;
    const int drow = ti*16 + (lane>>4)*4;
    #pragma unroll
    for (int tj = 0; tj < 2; ++tj)
      #pragma unroll
      for (int rr = 0; rr < 4; ++rr)
        atomicAdd(&cb[(drow + rr)*32 + tj*16 + fr], acc2[tj][rr]);
    if (fr == 0){
      float* zb = zu + (((size_t)frame*8 + slot)*8 + head)*32;
      #pragma unroll
      for (int rr = 0; rr < 4; ++rr)
        atomicAdd(&zb[drow + rr], zacc[rr]);
    }
  }
}

// ---------- sum 8 slots once per frame: ctxs[f][8192], zs[f][256]; grid (8h, f) ----------
__global__ __launch_bounds__(256) void k_ctxsum(const float* __restrict__ ctxu, const float* __restrict__ zu,
    float* __restrict__ ctxs, float* __restrict__ zs){
  const int h = blockIdx.x, frel = blockIdx.y, t = threadIdx.x;
  if (t < 32){
    float s = 0.f;
    #pragma unroll
    for (int sl = 0; sl < 8; ++sl) s += zu[(((size_t)frel*8 + sl)*8 + h)*32 + t];
    zs[frel*256 + h*32 + t] = s;
  }
  for (int i = t; i < 1024; i += 256){
    float s = 0.f;
    #pragma unroll
    for (int sl = 0; sl < 8; ++sl) s += ctxu[(((size_t)frel*8 + sl)*8 + h)*1024 + i];
    ctxs[(size_t)frel*8192 + h*1024 + i] = s;
  }
}

// ---------- output GEMM: out = qs @ Weff_f^T + bc + resid, LDS-transpose epilogue ----------
__global__ __launch_bounds__(256, 3) void k_gemm_out(const u16* __restrict__ A, const u16* __restrict__ B,
    float* __restrict__ Cf, const float* __restrict__ bias, const u16* __restrict__ residb,
    int M, int NB, int frame_rows){
  constexpr int K = 256, N = 256, NT = 8;
  __shared__ __align__(16) u16 pool[24576];
  u16* As = pool;
  u16* Bs = pool + 12288;
  const int t = threadIdx.x;
  const int wave = t >> 6, lane = t & 63;
  const int bi = blockIdx.x;
  const int xk = bi & 7, bj = bi >> 3;
  const int bm = (xk + 8*(bj/NB)) * 128, bn = (bj%NB) * 128;
  if (frame_rows > 0) B += (size_t)(bm / frame_rows) * N * K;
  const int srow = wave*32 + (lane>>2);
  const int skel = (((lane&3) ^ ((lane>>3)&3)) << 3);
  const u16* ag = A + (size_t)(bm + srow)*K + skel;
  const u16* bg = B + (size_t)(bn + srow)*K + skel;
  const size_t rstep = (size_t)16*K;
  const int wr = (wave>>1)*64, wc4 = (wave&1)*64;
  const int fr = lane & 15;
  const int fkc = lane >> 4;
  const int koff = ((fkc ^ ((fr>>1)&3)) << 3);
  f32x4 acc[4][4] = {};
  #pragma unroll
  for (int pre = 0; pre < 2; ++pre){
    u16* asl = As + pre*4096 + wave*1024; u16* bsl = Bs + pre*4096 + wave*1024;
    const int k0 = pre*32;
    GLOAD_LDS16(ag + k0,         asl);
    GLOAD_LDS16(ag + rstep + k0, asl + 512);
    GLOAD_LDS16(bg + k0,         bsl);
    GLOAD_LDS16(bg + rstep + k0, bsl + 512);
  }
  #pragma unroll
  for (int it = 0; it < NT; ++it){
    const int cur = it % 3;
    if (it == NT-1) { asm volatile("s_waitcnt vmcnt(0)" ::: "memory"); }
    else            { asm volatile("s_waitcnt vmcnt(4)" ::: "memory"); }
    __builtin_amdgcn_s_barrier();
    __builtin_amdgcn_sched_barrier(0);
    short8 av[4], bv[4];
    #pragma unroll
    for (int m = 0; m < 4; ++m)
      av[m] = *(const short8*)&As[cur*4096 + (wr + m*16 + fr)*32 + koff];
    #pragma unroll
    for (int n = 0; n < 4; ++n)
      bv[n] = *(const short8*)&Bs[cur*4096 + (wc4 + n*16 + fr)*32 + koff];
    if (it + 2 < NT){
      const int nb = (it+2) % 3;
      u16* asl = As + nb*4096 + wave*1024; u16* bsl = Bs + nb*4096 + wave*1024;
      const int k0 = (it+2)*32;
      GLOAD_LDS16(ag + k0,         asl);
      GLOAD_LDS16(ag + rstep + k0, asl + 512);
      GLOAD_LDS16(bg + k0,         bsl);
      GLOAD_LDS16(bg + rstep + k0, bsl + 512);
    }
    __builtin_amdgcn_s_setprio(1);
    #pragma unroll
    for (int m = 0; m < 4; ++m)
      #pragma unroll
      for (int n = 0; n < 4; ++n)
        acc[m][n] = __builtin_amdgcn_mfma_f32_16x16x32_bf16(av[m], bv[n], acc[m][n], 0, 0, 0);
    __builtin_amdgcn_s_setprio(0);
  }
  __syncthreads();
  float* cmatf = (float*)pool;
  const int lr0 = (lane>>4)*4;
  float biasr[32];
  {
    const int c0 = bn + (t&3)*32;
    #pragma unroll
    for (int c4 = 0; c4 < 8; ++c4)
      *(float4*)&biasr[c4*4] = *(const float4*)&bias[c0 + c4*4];
  }
  #pragma unroll
  for (int half = 0; half < 2; ++half){
    if ((wr >> 6) == half){
      #pragma unroll
      for (int m = 0; m < 4; ++m)
        #pragma unroll
        for (int n = 0; n < 4; ++n)
          #pragma unroll
          for (int r = 0; r < 4; ++r)
            cmatf[(lr0 + m*16 + r)*132 + wc4 + n*16 + fr] = acc[m][n][r];
    }
    __syncthreads();
    {
      const int row = t >> 2, seg = (t & 3) * 32;
      const int gr = bm + half*64 + row;
      const size_t gbase = (size_t)gr*256 + bn + seg;
      float v[32];
      #pragma unroll
      for (int c4 = 0; c4 < 8; ++c4)
        *(float4*)&v[c4*4] = *(const float4*)&cmatf[row*132 + seg + c4*4];
      #pragma unroll
      for (int c4 = 0; c4 < 4; ++c4){
        short8 rr = *(const short8*)&residb[gbase + c4*8];
        #pragma unroll
        for (int k2 = 0; k2 < 8; ++k2)
          v[c4*8+k2] += biasr[c4*8+k2] + b2f((u16)rr[k2]);
      }
      #pragma unroll
      for (int c4 = 0; c4 < 8; ++c4)
        *(float4*)&Cf[gbase + c4*4] = *(float4*)&v[c4*4];
    }
    __syncthreads();
  }
}

// ---------- Weff: grid (256 l, 8f); reads summed ctx + z, folds 1/Z ----------
__global__ __launch_bounds__(256) void k_weff(const float* __restrict__ ctxs, const float* __restrict__ zs,
    const float* __restrict__ wcf, u16* __restrict__ weff){
  int l = blockIdx.x, frel = blockIdx.y, t = threadIdx.x;
  int h = t >> 5, dd = t & 31;
  const float* cr = ctxs + (size_t)frel*8192 + h*1024 + dd*32;
  const float* wr = wcf + (size_t)l*256 + h*32;
  float s = 0.f;
  #pragma unroll
  for (int e = 0; e < 32; ++e) s += cr[e] * wr[e];
  float iz = 1.0f / zs[frel*256 + t];
  weff[((size_t)frel*256 + l)*256 + t] = f2b(s * iz);
}

extern "C" void kernel_launch(void* const* d_in, const int* in_sizes, int n_in,
                              void* d_out, int out_size, void* d_ws, size_t ws_size,
                              hipStream_t stream){
  const float* x     = (const float*)d_in[0];
  const float* w_qkv = (const float*)d_in[1];
  const float* w_out = (const float*)d_in[2];
  const float* b_out = (const float*)d_in[3];
  const float* w_lin = (const float*)d_in[4];
  const float* b_lin = (const float*)d_in[5];
  float* out = (float*)d_out;

  char* p = (char*)d_ws;
  u16*   wqb   = (u16*)p;   p += (size_t)768*256*2;
  float* wcf   = (float*)p; p += (size_t)256*256*4;
  float* bc    = (float*)p; p += 256*4;
  float* ctxu  = (float*)p; p += (size_t)8*8*8192*4;   // [f][slot][8][1024]
  float* zu    = (float*)p; p += (size_t)8*8*256*4;    // [f][slot][8][32]
  float* ctxs  = (float*)p; p += (size_t)8*8192*4;
  float* zs    = (float*)p; p += (size_t)8*256*4;
  u16*   weffb = (u16*)p;   p += (size_t)8*256*256*2;
  size_t fixed = (size_t)(p - (char*)d_ws);
  size_t per_frame = (size_t)2 * 9216*256*2;   // xb + qs
  int chunk = (ws_size >= fixed + 8*per_frame) ? 8 : 1;
  u16* xb  = (u16*)p;
  u16* qsb = xb  + (size_t)chunk*9216*256;

  // zero atomic accumulators (ctxu + zu contiguous)
  hipMemsetAsync(ctxu, 0, (size_t)8*8*8192*4 + (size_t)8*8*256*4, stream);

  // weight prep (once)
  hipLaunchKernelGGL(k_prep, dim3(1024), dim3(256), 0, stream,
                     w_qkv, w_lin, w_out, b_out, b_lin, wqb, wcf, bc);

  for (int f0 = 0; f0 < 8; f0 += chunk){
    const float* xc = x  + (size_t)f0*9216*256;
    float*       oc = out + (size_t)f0*9216*256;
    const int M = chunk * 9216;
    const int n4 = M * 256 / 4;
    hipLaunchKernelGGL(k_cvt, dim3((n4 + 255)/256), dim3(256), 0, stream, (const float4*)xc, (ushort4*)xb, n4);
    hipLaunchKernelGGL(k_gemm_qkv, dim3((M/128)*6), dim3(256), 0, stream,
                       xb, wqb, qsb, ctxu + (size_t)f0*8*8192, zu + (size_t)f0*8*256, M);
    hipLaunchKernelGGL(k_ctxsum, dim3(8, chunk), dim3(256), 0, stream,
                       ctxu + (size_t)f0*8*8192, zu + (size_t)f0*8*256,
                       ctxs + (size_t)f0*8192, zs + (size_t)f0*256);
    hipLaunchKernelGGL(k_weff, dim3(256, chunk), dim3(256), 0, stream,
                       ctxs + (size_t)f0*8192, zs + (size_t)f0*256, wcf, weffb + (size_t)f0*256*256);
    hipLaunchKernelGGL(k_gemm_out, dim3((M/128)*2), dim3(256), 0, stream,
                       qsb, weffb + (size_t)f0*256*256, oc, bc, xb,
                       M, 2, (chunk == 8) ? 9216 : 0);
  }
}